// Round 16
// baseline (380.574 us; speedup 1.0000x reference)
//
#include <hip/hip_runtime.h>
#include <hip/hip_fp16.h>
#include <hip/hip_fp8.h>
#include <math.h>

#define NN 50000
#define EE 800000
#define DD 128

typedef __attribute__((ext_vector_type(8))) _Float16 half8;
typedef __attribute__((ext_vector_type(2))) _Float16 h2;
typedef __attribute__((ext_vector_type(4))) float f32x4;
typedef __attribute__((ext_vector_type(2))) float f32x2;

#if __has_builtin(__builtin_amdgcn_fdot2)
#define FDOT2(a,b,c) __builtin_amdgcn_fdot2((a),(b),(c),false)
#else
static __device__ __forceinline__ float FDOT2(h2 a, h2 b, float c){
  return c + (float)a[0]*(float)b[0] + (float)a[1]*(float)b[1];
}
#endif

// ---- fp8 e4m3 pack/unpack (HW path on gfx950, scalar fallback otherwise) ----
static __device__ __forceinline__ unsigned int enc_fp8x4(float a, float b, float c, float d){
#if __has_builtin(__builtin_amdgcn_cvt_pk_fp8_f32)
  int v = __builtin_amdgcn_cvt_pk_fp8_f32(a, b, 0, false);
  v = __builtin_amdgcn_cvt_pk_fp8_f32(c, d, v, true);
  return (unsigned int)v;
#else
  __hip_fp8_e4m3 e0(a), e1(b), e2(c), e3(d);
  return (unsigned int)e0.__x | ((unsigned int)e1.__x << 8) |
         ((unsigned int)e2.__x << 16) | ((unsigned int)e3.__x << 24);
#endif
}

#if __has_builtin(__builtin_amdgcn_cvt_pk_f32_fp8)
static __device__ __forceinline__ f32x2 dec_fp8_lo(unsigned int w){
  return __builtin_amdgcn_cvt_pk_f32_fp8((int)w, false);
}
static __device__ __forceinline__ f32x2 dec_fp8_hi(unsigned int w){
  return __builtin_amdgcn_cvt_pk_f32_fp8((int)w, true);
}
#else
static __device__ __forceinline__ float dec1_fp8(unsigned int b){
  int s = (b >> 7) & 1, e = (b >> 3) & 15, m = b & 7;
  float v = (e == 0) ? (m * 0.001953125f) : ((1.0f + m*0.125f) * exp2f((float)(e-7)));
  return s ? -v : v;
}
static __device__ __forceinline__ f32x2 dec_fp8_lo(unsigned int w){
  f32x2 r; r[0] = dec1_fp8(w & 0xFF); r[1] = dec1_fp8((w>>8) & 0xFF); return r;
}
static __device__ __forceinline__ f32x2 dec_fp8_hi(unsigned int w){
  f32x2 r; r[0] = dec1_fp8((w>>16) & 0xFF); r[1] = dec1_fp8((w>>24) & 0xFF); return r;
}
#endif

// ======================= CSR build =======================

__global__ void zero_kernel(int* __restrict__ p, int n){
  int i = blockIdx.x*blockDim.x + threadIdx.x;
  if (i < n) p[i] = 0;
}

// histogram + per-edge rank (atomicAdd return = arrival rank within dst)
__global__ void hist_kernel(const int* __restrict__ edst, int* __restrict__ deg,
                            int* __restrict__ rank, int e){
  int i = blockIdx.x*blockDim.x + threadIdx.x;
  if (i < e) rank[i] = atomicAdd(&deg[edst[i]], 1);
}

__global__ void scan_partial(const int* __restrict__ deg, int* __restrict__ bsum, int n){
  __shared__ int s[256];
  int t = threadIdx.x;
  int i = blockIdx.x*256 + t;
  s[t] = (i < n) ? deg[i] : 0;
  __syncthreads();
  for (int o = 128; o > 0; o >>= 1){
    if (t < o) s[t] += s[t+o];
    __syncthreads();
  }
  if (t == 0) bsum[blockIdx.x] = s[0];
}

__global__ void scan_bsums(int* __restrict__ bsum, int nb){
  __shared__ int s[256];
  int t = threadIdx.x;
  int v = (t < nb) ? bsum[t] : 0;
  s[t] = v;
  __syncthreads();
  for (int o = 1; o < 256; o <<= 1){
    int x = (t >= o) ? s[t-o] : 0;
    __syncthreads();
    s[t] += x;
    __syncthreads();
  }
  if (t < nb) bsum[t] = s[t] - v;   // exclusive
}

__global__ void scan_apply(const int* __restrict__ deg, const int* __restrict__ bsum,
                           int* __restrict__ off, int n){
  __shared__ int s[256];
  int t = threadIdx.x;
  int i = blockIdx.x*256 + t;
  int v = (i < n) ? deg[i] : 0;
  s[t] = v;
  __syncthreads();
  for (int o = 1; o < 256; o <<= 1){
    int x = (t >= o) ? s[t-o] : 0;
    __syncthreads();
    s[t] += x;
    __syncthreads();
  }
  if (i < n) off[i] = s[t] - v + bsum[blockIdx.x];
}

// atomic-free scatter: position known from off + rank
__global__ void scatter_kernel(const int* __restrict__ esrc, const int* __restrict__ edst,
                               const int* __restrict__ rank, const int* __restrict__ off,
                               int* __restrict__ csr_src, int e){
  int i = blockIdx.x*blockDim.x + threadIdx.x;
  if (i < e)
    csr_src[off[edst[i]] + rank[i]] = esrc[i];
}

// ======================= prep: weights -> transposed fp16, x -> fp16 =======================
__global__ void prep_w(const float* __restrict__ Wq, const float* __restrict__ Wk,
                       const float* __restrict__ Wv, const float* __restrict__ Ws,
                       const float* __restrict__ bq, const float* __restrict__ bk,
                       const float* __restrict__ bv, const float* __restrict__ bs,
                       const float* __restrict__ Wout,
                       __half* __restrict__ wt, float* __restrict__ bcat,
                       __half* __restrict__ wtout){
  int idx = blockIdx.x*256 + threadIdx.x;
  if (idx < 4*512*128){
    int l = idx >> 16;
    int rem = idx & 65535;
    int n = rem >> 7;
    int k = rem & 127;
    int mat = n >> 7;
    int nn = n & 127;
    const float* W = (mat==0)?Wq:(mat==1)?Wk:(mat==2)?Wv:Ws;
    wt[idx] = __float2half(W[l*16384 + k*128 + nn]);
  }
  if (idx < 128*128){
    int n = idx >> 7, k = idx & 127;
    wtout[idx] = __float2half(Wout[k*128 + n]);
  }
  if (idx < 4*512){
    int l = idx >> 9, n = idx & 511;
    int mat = n >> 7, nn = n & 127;
    const float* B = (mat==0)?bq:(mat==1)?bk:(mat==2)?bv:bs;
    bcat[idx] = B[l*128 + nn];
  }
}

__global__ void convert_x(const float* __restrict__ x, __half* __restrict__ xh, int n8){
  int i = blockIdx.x*256 + threadIdx.x;
  if (i < n8){
    float4 f0 = *(const float4*)&x[(size_t)i*8];
    float4 f1 = *(const float4*)&x[(size_t)i*8+4];
    __half2 h[4] = {__floats2half2_rn(f0.x,f0.y), __floats2half2_rn(f0.z,f0.w),
                    __floats2half2_rn(f1.x,f1.y), __floats2half2_rn(f1.z,f1.w)};
    *(int4*)&xh[(size_t)i*8] = *(const int4*)h;
  }
}

// ======================= MFMA GEMM (fused 4 mats, 8 waves/block) =======================
// Block: 512 threads = 8 waves, tile 64 rows x 128 cols; wave = 32x32 quadrant
// (wr = w>>2, wc = w&3), acc = 2x2 f32x4 frags. LDS 48KB -> 3 blocks/CU.
// FMODE 0 outputs: q[NN][128] fp16, skip[NN][128] fp16,
//   kv record per node = 384B: [k 128ch fp8-e4m3 | v 128ch fp16].
// FMODE 1: 1 mat, fp32 node-major out (final projection).
template<int FMODE>
__global__ __launch_bounds__(512) void mfma_gemm(
    const __half* __restrict__ xh, const __half* __restrict__ wt,
    const float* __restrict__ bias,
    __half* __restrict__ oq, unsigned char* __restrict__ okv, __half* __restrict__ osk,
    float* __restrict__ ofp, int nrows)
{
  __shared__ __half a_lds[64*128];    // 16 KB
  __shared__ __half b_lds[128*128];   // 32 KB (also epilogue buffer)

  const int tid = threadIdx.x;
  const int m0 = blockIdx.x * 64;
  const int lane = tid & 63;
  const int w  = tid >> 6;            // 0..7
  const int wr = w >> 2, wc = w & 3;  // wave quadrant: 2 row x 4 col
  const int li = lane & 15, lg = lane >> 4;

  // ---- stage A once: 64 rows x 16 chunks = 1024 -> 2 passes of 512 ----
  #pragma unroll
  for (int p = 0; p < 2; p++){
    int chunk = tid + p*512;
    int row = chunk >> 4;
    int cs  = chunk & 15;
    int gm = m0 + row;
    int4 va = make_int4(0,0,0,0);
    if (gm < nrows) va = *(const int4*)&xh[(size_t)gm*DD + cs*8];
    *(int4*)&a_lds[row*128 + (cs ^ (row & 7))*8] = va;
  }

  const int NMATS = (FMODE == 0) ? 4 : 1;
  for (int mat = 0; mat < NMATS; mat++){
    // ---- stage B(mat): 128 rows x 16 chunks = 2048 -> 4 passes ----
    #pragma unroll
    for (int p = 0; p < 4; p++){
      int chunk = tid + p*512;
      int row = chunk >> 4;
      int cs  = chunk & 15;
      int4 vb = *(const int4*)&wt[(size_t)(mat*128 + row)*DD + cs*8];
      *(int4*)&b_lds[row*128 + (cs ^ (row & 7))*8] = vb;
    }
    __syncthreads();

    f32x4 acc[2][2];
    #pragma unroll
    for (int fn = 0; fn < 2; fn++){
      float b = bias[mat*128 + wc*32 + fn*16 + li];
      #pragma unroll
      for (int fm = 0; fm < 2; fm++)
        acc[fm][fn] = (f32x4){b, b, b, b};
    }

    #pragma unroll
    for (int kk = 0; kk < 4; kk++){
      half8 af[2], bf[2];
      #pragma unroll
      for (int fm = 0; fm < 2; fm++){
        int row = wr*32 + fm*16 + li;
        int chunk = kk*4 + lg;
        af[fm] = *(half8*)&a_lds[row*128 + (chunk ^ (row & 7))*8];
      }
      #pragma unroll
      for (int fn = 0; fn < 2; fn++){
        int row = wc*32 + fn*16 + li;
        int chunk = kk*4 + lg;
        bf[fn] = *(half8*)&b_lds[row*128 + (chunk ^ (row & 7))*8];
      }
      #pragma unroll
      for (int fm = 0; fm < 2; fm++)
        #pragma unroll
        for (int fn = 0; fn < 2; fn++)
          acc[fm][fn] = __builtin_amdgcn_mfma_f32_16x16x32_f16(af[fm], bf[fn], acc[fm][fn], 0, 0, 0);
    }
    __syncthreads();   // done reading b_lds as B; reuse as epilogue buffer

    if (FMODE == 0){
      #pragma unroll
      for (int fm = 0; fm < 2; fm++)
        #pragma unroll
        for (int fn = 0; fn < 2; fn++)
          #pragma unroll
          for (int r = 0; r < 4; r++){
            int row = wr*32 + fm*16 + lg*4 + r;
            int col = wc*32 + fn*16 + li;
            int chunk = col >> 3, within = col & 7;
            b_lds[row*128 + (chunk ^ (row & 7))*8 + within] = __float2half(acc[fm][fn][r]);
          }
      __syncthreads();
      // 64 rows x 16 chunks = 1024 chunks = 2 passes of 512 threads
      #pragma unroll
      for (int p = 0; p < 2; p++){
        int chunk = tid + p*512;
        int row = chunk >> 4, cs = chunk & 15;
        int gm = m0 + row;
        if (gm < nrows){
          int4 val = *(int4*)&b_lds[row*128 + (cs ^ (row & 7))*8];
          if (mat == 0)      *(int4*)&oq [(size_t)gm*128 + cs*8] = val;
          else if (mat == 3) *(int4*)&osk[(size_t)gm*128 + cs*8] = val;
          else if (mat == 2) *(int4*)&okv[(size_t)gm*384 + 128 + cs*16] = val;  // v fp16
          else {
            // k -> fp8 e4m3: 8 halves -> 8 bytes
            const __half2* hv = (const __half2*)&val;
            float2 f0 = __half22float2(hv[0]);
            float2 f1 = __half22float2(hv[1]);
            float2 f2 = __half22float2(hv[2]);
            float2 f3 = __half22float2(hv[3]);
            int2 wv;
            wv.x = (int)enc_fp8x4(f0.x, f0.y, f1.x, f1.y);
            wv.y = (int)enc_fp8x4(f2.x, f2.y, f3.x, f3.y);
            *(int2*)&okv[(size_t)gm*384 + cs*8] = wv;
          }
        }
      }
      __syncthreads();   // stores' LDS reads done before next B stage
    } else {
      float* f_lds = (float*)b_lds;   // 64x128 f32 = 32 KB
      #pragma unroll
      for (int fm = 0; fm < 2; fm++)
        #pragma unroll
        for (int fn = 0; fn < 2; fn++)
          #pragma unroll
          for (int r = 0; r < 4; r++){
            int row = wr*32 + fm*16 + lg*4 + r;
            int col = wc*32 + fn*16 + li;
            int chunk = col >> 2, within = col & 3;
            f_lds[row*128 + (chunk ^ (row & 7))*4 + within] = acc[fm][fn][r];
          }
      __syncthreads();
      // 64 rows x 32 fp32-chunks = 2048 chunks = 4 passes
      #pragma unroll
      for (int p = 0; p < 4; p++){
        int chunk = tid + p*512;
        int row = chunk >> 5, cs = chunk & 31;
        int gm = m0 + row;
        if (gm < nrows)
          *(int4*)&ofp[(size_t)gm*DD + cs*4] = *(int4*)&f_lds[row*128 + (cs ^ (row & 7))*4];
      }
    }
  }
}

// ======================= per-node attention aggregation (fp8 k, persistent waves) =======================
// Grid-stride: 2048 blocks x 4 waves; each wave loops over ~6 dst nodes, so
// CUs stay full (fixes 42% occupancy from short-lived blocks). Per node:
// 8 sub-streams of 8 lanes, lane owns ONE head's 16 channels. kv record =
// 384B: [k fp8 128B | v fp16 256B]. No online max; 1-deep prefetch.
__global__ __launch_bounds__(256) void agg_kernel(
    const __half* __restrict__ hq, const __half* __restrict__ hsk,
    const unsigned char* __restrict__ kv,
    const int* __restrict__ off, const int* __restrict__ csr_src,
    __half* __restrict__ xout, int n)
{
  const int nwaves = gridDim.x * 4;
  const int wslot  = blockIdx.x*4 + (threadIdx.x >> 6);
  const int lane = threadIdx.x & 63;
  const int sub  = lane >> 3;          // 0..7: edge sub-stream
  const int h    = lane & 7;           // head index
  const int c    = h*16;               // 16 channels per head per lane

  for (int wid = wslot; wid < n; wid += nwaves){
    float qf[16];
    {
      int4 q0 = *(const int4*)&hq[(size_t)wid*DD + c];
      int4 q1 = *(const int4*)&hq[(size_t)wid*DD + c + 8];
      const __half2* qh = (const __half2*)&q0;
      #pragma unroll
      for (int i = 0; i < 4; i++){
        float2 f = __half22float2(qh[i]);
        qf[2*i] = f.x; qf[2*i+1] = f.y;
      }
      const __half2* qh1 = (const __half2*)&q1;
      #pragma unroll
      for (int i = 0; i < 4; i++){
        float2 f = __half22float2(qh1[i]);
        qf[8+2*i] = f.x; qf[8+2*i+1] = f.y;
      }
    }

    float z = 0.f;
    float acc[16];
    #pragma unroll
    for (int i = 0; i < 16; i++) acc[i] = 0.f;

    const int e1 = off[wid+1];
    int e = off[wid] + sub;
    int s2 = (e+8 < e1) ? csr_src[e+8] : -1;
    int4 kr, v0r, v1r;
    if (e < e1){
      const unsigned char* r = kv + (size_t)csr_src[e]*384;
      kr  = *(const int4*)(r + h*16);
      v0r = *(const int4*)(r + 128 + h*32);
      v1r = *(const int4*)(r + 144 + h*32);
    }
    while (e < e1){
      int4 kn, v0n, v1n;
      if (s2 >= 0){
        const unsigned char* r = kv + (size_t)s2*384;
        kn  = *(const int4*)(r + h*16);
        v0n = *(const int4*)(r + 128 + h*32);
        v1n = *(const int4*)(r + 144 + h*32);
      }
      int s3 = (e+16 < e1) ? csr_src[e+16] : -1;

      // decode 16 fp8 k values and dot with qf
      const unsigned int* kw = (const unsigned int*)&kr;
      float p = 0.f;
      #pragma unroll
      for (int i = 0; i < 4; i++){
        f32x2 a = dec_fp8_lo(kw[i]);
        f32x2 b = dec_fp8_hi(kw[i]);
        p += qf[4*i]*a[0] + qf[4*i+1]*a[1] + qf[4*i+2]*b[0] + qf[4*i+3]*b[1];
      }
      float wgt = __expf(p * 0.25f);     // 1/sqrt(16); no max subtraction

      const __half2* vh0 = (const __half2*)&v0r;
      const __half2* vh1 = (const __half2*)&v1r;
      #pragma unroll
      for (int i = 0; i < 4; i++){
        float2 f = __half22float2(vh0[i]);
        acc[2*i]   += wgt * f.x;
        acc[2*i+1] += wgt * f.y;
      }
      #pragma unroll
      for (int i = 0; i < 4; i++){
        float2 f = __half22float2(vh1[i]);
        acc[8+2*i]   += wgt * f.x;
        acc[8+2*i+1] += wgt * f.y;
      }
      z += wgt;

      kr = kn; v0r = v0n; v1r = v1n;
      s2 = s3; e += 8;
    }

    // merge 8 sub-streams (pure sums)
    #pragma unroll
    for (int d = 8; d <= 32; d <<= 1){
      z += __shfl_xor(z, d);
      #pragma unroll
      for (int i = 0; i < 16; i++)
        acc[i] += __shfl_xor(acc[i], d);
    }

    if (sub == 0){
      float inv = (z > 0.f) ? 1.f/z : 0.f;
      int4 s0 = *(const int4*)&hsk[(size_t)wid*DD + c];
      int4 s1 = *(const int4*)&hsk[(size_t)wid*DD + c + 8];
      const __half2* sh0 = (const __half2*)&s0;
      const __half2* sh1 = (const __half2*)&s1;
      __half2 po[4];
      #pragma unroll
      for (int i = 0; i < 4; i++){
        float2 s = __half22float2(sh0[i]);
        po[i] = __floats2half2_rn(fmaxf(acc[2*i]*inv + s.x, 0.f),
                                  fmaxf(acc[2*i+1]*inv + s.y, 0.f));
      }
      *(int4*)&xout[(size_t)wid*DD + c] = *(const int4*)po;
      #pragma unroll
      for (int i = 0; i < 4; i++){
        float2 s = __half22float2(sh1[i]);
        po[i] = __floats2half2_rn(fmaxf(acc[8+2*i]*inv + s.x, 0.f),
                                  fmaxf(acc[8+2*i+1]*inv + s.y, 0.f));
      }
      *(int4*)&xout[(size_t)wid*DD + c + 8] = *(const int4*)po;
    }
  }
}

// ======================= launch =======================

extern "C" void kernel_launch(void* const* d_in, const int* in_sizes, int n_in,
                              void* d_out, int out_size, void* d_ws, size_t ws_size,
                              hipStream_t stream) {
  const float* x     = (const float*)d_in[0];
  const int*   edge  = (const int*)d_in[1];
  const int*   esrc  = edge;
  const int*   edst  = edge + EE;
  const float* Wq    = (const float*)d_in[3];
  const float* bq    = (const float*)d_in[4];
  const float* Wk    = (const float*)d_in[5];
  const float* bk    = (const float*)d_in[6];
  const float* Wv    = (const float*)d_in[7];
  const float* bv    = (const float*)d_in[8];
  const float* Wsk   = (const float*)d_in[9];
  const float* bsk   = (const float*)d_in[10];
  const float* Wout  = (const float*)d_in[11];
  const float* bout  = (const float*)d_in[12];
  float* out = (float*)d_out;

  uintptr_t base = (uintptr_t)d_ws;
  auto align = [](uintptr_t p){ return (p + 255) & ~(uintptr_t)255; };
  int* deg    = (int*)base;  base = align(base + (NN+1)*sizeof(int));
  int* off    = (int*)base;  base = align(base + (NN+1)*sizeof(int));
  int* rank   = (int*)base;  base = align(base + (size_t)EE*sizeof(int));
  int* bsum   = (int*)base;  base = align(base + 256*sizeof(int));
  int* csr    = (int*)base;  base = align(base + (size_t)EE*sizeof(int));
  __half* xh   = (__half*)base; base = align(base + (size_t)NN*DD*sizeof(__half));
  __half* xbuf = (__half*)base; base = align(base + (size_t)NN*DD*sizeof(__half));
  __half* hq   = (__half*)base; base = align(base + (size_t)NN*DD*sizeof(__half));
  __half* hsk  = (__half*)base; base = align(base + (size_t)NN*DD*sizeof(__half));
  unsigned char* kvb = (unsigned char*)base; base = align(base + (size_t)NN*384);
  __half* wt   = (__half*)base; base = align(base + (size_t)4*512*128*sizeof(__half));
  __half* wtout= (__half*)base; base = align(base + (size_t)128*128*sizeof(__half));
  float*  bcat = (float*)base;  base = align(base + (size_t)4*512*sizeof(float));

  const int NP = NN + 1;
  const int SCAN_BLKS = (NP + 255)/256;

  zero_kernel<<<SCAN_BLKS, 256, 0, stream>>>(deg, NP);
  hist_kernel<<<(EE+255)/256, 256, 0, stream>>>(edst, deg, rank, EE);
  scan_partial<<<SCAN_BLKS, 256, 0, stream>>>(deg, bsum, NP);
  scan_bsums<<<1, 256, 0, stream>>>(bsum, SCAN_BLKS);
  scan_apply<<<SCAN_BLKS, 256, 0, stream>>>(deg, bsum, off, NP);
  scatter_kernel<<<(EE+255)/256, 256, 0, stream>>>(esrc, edst, rank, off, csr, EE);

  prep_w<<<1024, 256, 0, stream>>>(Wq, Wk, Wv, Wsk, bq, bk, bv, bsk, Wout, wt, bcat, wtout);
  convert_x<<<(NN*DD/8 + 255)/256, 256, 0, stream>>>(x, xh, NN*DD/8);

  const int MT64 = (NN + 63)/64;   // 782 row tiles
  const int AGG_BLKS = 2048;       // persistent: 8 waves/CU x 256 CU / 4 waves/block
  const __half* xin = xh;
  for (int l = 0; l < 4; l++){
    mfma_gemm<0><<<MT64, 512, 0, stream>>>(
        xin, wt + (size_t)l*512*128, bcat + l*512,
        hq, kvb, hsk, nullptr, NN);
    agg_kernel<<<AGG_BLKS, 256, 0, stream>>>(hq, hsk, kvb, off, csr, xbuf, NN);
    xin = xbuf;
  }
  mfma_gemm<1><<<MT64, 512, 0, stream>>>(
      xin, wtout, bout, nullptr, kvb, nullptr, out, NN);
}

// Round 17
// 368.192 us; speedup vs baseline: 1.0336x; 1.0336x over previous
//
#include <hip/hip_runtime.h>
#include <hip/hip_fp16.h>
#include <hip/hip_fp8.h>
#include <math.h>

#define NN 50000
#define EE 800000
#define DD 128

typedef __attribute__((ext_vector_type(8))) _Float16 half8;
typedef __attribute__((ext_vector_type(2))) _Float16 h2;
typedef __attribute__((ext_vector_type(4))) float f32x4;
typedef __attribute__((ext_vector_type(2))) float f32x2;

#if __has_builtin(__builtin_amdgcn_fdot2)
#define FDOT2(a,b,c) __builtin_amdgcn_fdot2((a),(b),(c),false)
#else
static __device__ __forceinline__ float FDOT2(h2 a, h2 b, float c){
  return c + (float)a[0]*(float)b[0] + (float)a[1]*(float)b[1];
}
#endif

// ---- fp8 e4m3 pack/unpack (HW path on gfx950, scalar fallback otherwise) ----
static __device__ __forceinline__ unsigned int enc_fp8x4(float a, float b, float c, float d){
#if __has_builtin(__builtin_amdgcn_cvt_pk_fp8_f32)
  int v = __builtin_amdgcn_cvt_pk_fp8_f32(a, b, 0, false);
  v = __builtin_amdgcn_cvt_pk_fp8_f32(c, d, v, true);
  return (unsigned int)v;
#else
  __hip_fp8_e4m3 e0(a), e1(b), e2(c), e3(d);
  return (unsigned int)e0.__x | ((unsigned int)e1.__x << 8) |
         ((unsigned int)e2.__x << 16) | ((unsigned int)e3.__x << 24);
#endif
}

#if __has_builtin(__builtin_amdgcn_cvt_pk_f32_fp8)
static __device__ __forceinline__ f32x2 dec_fp8_lo(unsigned int w){
  return __builtin_amdgcn_cvt_pk_f32_fp8((int)w, false);
}
static __device__ __forceinline__ f32x2 dec_fp8_hi(unsigned int w){
  return __builtin_amdgcn_cvt_pk_f32_fp8((int)w, true);
}
#else
static __device__ __forceinline__ float dec1_fp8(unsigned int b){
  int s = (b >> 7) & 1, e = (b >> 3) & 15, m = b & 7;
  float v = (e == 0) ? (m * 0.001953125f) : ((1.0f + m*0.125f) * exp2f((float)(e-7)));
  return s ? -v : v;
}
static __device__ __forceinline__ f32x2 dec_fp8_lo(unsigned int w){
  f32x2 r; r[0] = dec1_fp8(w & 0xFF); r[1] = dec1_fp8((w>>8) & 0xFF); return r;
}
static __device__ __forceinline__ f32x2 dec_fp8_hi(unsigned int w){
  f32x2 r; r[0] = dec1_fp8((w>>16) & 0xFF); r[1] = dec1_fp8((w>>24) & 0xFF); return r;
}
#endif

// ======================= CSR build =======================

__global__ void zero_kernel(int* __restrict__ p, int n){
  int i = blockIdx.x*blockDim.x + threadIdx.x;
  if (i < n) p[i] = 0;
}

// histogram + per-edge rank (atomicAdd return = arrival rank within dst)
__global__ void hist_kernel(const int* __restrict__ edst, int* __restrict__ deg,
                            int* __restrict__ rank, int e){
  int i = blockIdx.x*blockDim.x + threadIdx.x;
  if (i < e) rank[i] = atomicAdd(&deg[edst[i]], 1);
}

__global__ void scan_partial(const int* __restrict__ deg, int* __restrict__ bsum, int n){
  __shared__ int s[256];
  int t = threadIdx.x;
  int i = blockIdx.x*256 + t;
  s[t] = (i < n) ? deg[i] : 0;
  __syncthreads();
  for (int o = 128; o > 0; o >>= 1){
    if (t < o) s[t] += s[t+o];
    __syncthreads();
  }
  if (t == 0) bsum[blockIdx.x] = s[0];
}

__global__ void scan_bsums(int* __restrict__ bsum, int nb){
  __shared__ int s[256];
  int t = threadIdx.x;
  int v = (t < nb) ? bsum[t] : 0;
  s[t] = v;
  __syncthreads();
  for (int o = 1; o < 256; o <<= 1){
    int x = (t >= o) ? s[t-o] : 0;
    __syncthreads();
    s[t] += x;
    __syncthreads();
  }
  if (t < nb) bsum[t] = s[t] - v;   // exclusive
}

__global__ void scan_apply(const int* __restrict__ deg, const int* __restrict__ bsum,
                           int* __restrict__ off, int n){
  __shared__ int s[256];
  int t = threadIdx.x;
  int i = blockIdx.x*256 + t;
  int v = (i < n) ? deg[i] : 0;
  s[t] = v;
  __syncthreads();
  for (int o = 1; o < 256; o <<= 1){
    int x = (t >= o) ? s[t-o] : 0;
    __syncthreads();
    s[t] += x;
    __syncthreads();
  }
  if (i < n) off[i] = s[t] - v + bsum[blockIdx.x];
}

// atomic-free scatter: position known from off + rank
__global__ void scatter_kernel(const int* __restrict__ esrc, const int* __restrict__ edst,
                               const int* __restrict__ rank, const int* __restrict__ off,
                               int* __restrict__ csr_src, int e){
  int i = blockIdx.x*blockDim.x + threadIdx.x;
  if (i < e)
    csr_src[off[edst[i]] + rank[i]] = esrc[i];
}

// ======================= prep: weights -> transposed fp16, x -> fp16 =======================
__global__ void prep_w(const float* __restrict__ Wq, const float* __restrict__ Wk,
                       const float* __restrict__ Wv, const float* __restrict__ Ws,
                       const float* __restrict__ bq, const float* __restrict__ bk,
                       const float* __restrict__ bv, const float* __restrict__ bs,
                       const float* __restrict__ Wout,
                       __half* __restrict__ wt, float* __restrict__ bcat,
                       __half* __restrict__ wtout){
  int idx = blockIdx.x*256 + threadIdx.x;
  if (idx < 4*512*128){
    int l = idx >> 16;
    int rem = idx & 65535;
    int n = rem >> 7;
    int k = rem & 127;
    int mat = n >> 7;
    int nn = n & 127;
    const float* W = (mat==0)?Wq:(mat==1)?Wk:(mat==2)?Wv:Ws;
    wt[idx] = __float2half(W[l*16384 + k*128 + nn]);
  }
  if (idx < 128*128){
    int n = idx >> 7, k = idx & 127;
    wtout[idx] = __float2half(Wout[k*128 + n]);
  }
  if (idx < 4*512){
    int l = idx >> 9, n = idx & 511;
    int mat = n >> 7, nn = n & 127;
    const float* B = (mat==0)?bq:(mat==1)?bk:(mat==2)?bv:bs;
    bcat[idx] = B[l*128 + nn];
  }
}

__global__ void convert_x(const float* __restrict__ x, __half* __restrict__ xh, int n8){
  int i = blockIdx.x*256 + threadIdx.x;
  if (i < n8){
    float4 f0 = *(const float4*)&x[(size_t)i*8];
    float4 f1 = *(const float4*)&x[(size_t)i*8+4];
    __half2 h[4] = {__floats2half2_rn(f0.x,f0.y), __floats2half2_rn(f0.z,f0.w),
                    __floats2half2_rn(f1.x,f1.y), __floats2half2_rn(f1.z,f1.w)};
    *(int4*)&xh[(size_t)i*8] = *(const int4*)h;
  }
}

// ======================= MFMA GEMM (fused 4 mats, 8 waves/block) =======================
// Block: 512 threads = 8 waves, tile 64 rows x 128 cols; wave = 32x32 quadrant
// (wr = w>>2, wc = w&3), acc = 2x2 f32x4 frags. LDS 48KB -> 3 blocks/CU.
// FMODE 0 outputs: q[NN][128] fp16, skip[NN][128] fp16,
//   kv record per node = 384B: [k 128ch fp8-e4m3 | v 128ch fp16].
// FMODE 1: 1 mat, fp32 node-major out (final projection).
template<int FMODE>
__global__ __launch_bounds__(512) void mfma_gemm(
    const __half* __restrict__ xh, const __half* __restrict__ wt,
    const float* __restrict__ bias,
    __half* __restrict__ oq, unsigned char* __restrict__ okv, __half* __restrict__ osk,
    float* __restrict__ ofp, int nrows)
{
  __shared__ __half a_lds[64*128];    // 16 KB
  __shared__ __half b_lds[128*128];   // 32 KB (also epilogue buffer)

  const int tid = threadIdx.x;
  const int m0 = blockIdx.x * 64;
  const int lane = tid & 63;
  const int w  = tid >> 6;            // 0..7
  const int wr = w >> 2, wc = w & 3;  // wave quadrant: 2 row x 4 col
  const int li = lane & 15, lg = lane >> 4;

  // ---- stage A once: 64 rows x 16 chunks = 1024 -> 2 passes of 512 ----
  #pragma unroll
  for (int p = 0; p < 2; p++){
    int chunk = tid + p*512;
    int row = chunk >> 4;
    int cs  = chunk & 15;
    int gm = m0 + row;
    int4 va = make_int4(0,0,0,0);
    if (gm < nrows) va = *(const int4*)&xh[(size_t)gm*DD + cs*8];
    *(int4*)&a_lds[row*128 + (cs ^ (row & 7))*8] = va;
  }

  const int NMATS = (FMODE == 0) ? 4 : 1;
  for (int mat = 0; mat < NMATS; mat++){
    // ---- stage B(mat): 128 rows x 16 chunks = 2048 -> 4 passes ----
    #pragma unroll
    for (int p = 0; p < 4; p++){
      int chunk = tid + p*512;
      int row = chunk >> 4;
      int cs  = chunk & 15;
      int4 vb = *(const int4*)&wt[(size_t)(mat*128 + row)*DD + cs*8];
      *(int4*)&b_lds[row*128 + (cs ^ (row & 7))*8] = vb;
    }
    __syncthreads();

    f32x4 acc[2][2];
    #pragma unroll
    for (int fn = 0; fn < 2; fn++){
      float b = bias[mat*128 + wc*32 + fn*16 + li];
      #pragma unroll
      for (int fm = 0; fm < 2; fm++)
        acc[fm][fn] = (f32x4){b, b, b, b};
    }

    #pragma unroll
    for (int kk = 0; kk < 4; kk++){
      half8 af[2], bf[2];
      #pragma unroll
      for (int fm = 0; fm < 2; fm++){
        int row = wr*32 + fm*16 + li;
        int chunk = kk*4 + lg;
        af[fm] = *(half8*)&a_lds[row*128 + (chunk ^ (row & 7))*8];
      }
      #pragma unroll
      for (int fn = 0; fn < 2; fn++){
        int row = wc*32 + fn*16 + li;
        int chunk = kk*4 + lg;
        bf[fn] = *(half8*)&b_lds[row*128 + (chunk ^ (row & 7))*8];
      }
      #pragma unroll
      for (int fm = 0; fm < 2; fm++)
        #pragma unroll
        for (int fn = 0; fn < 2; fn++)
          acc[fm][fn] = __builtin_amdgcn_mfma_f32_16x16x32_f16(af[fm], bf[fn], acc[fm][fn], 0, 0, 0);
    }
    __syncthreads();   // done reading b_lds as B; reuse as epilogue buffer

    if (FMODE == 0){
      #pragma unroll
      for (int fm = 0; fm < 2; fm++)
        #pragma unroll
        for (int fn = 0; fn < 2; fn++)
          #pragma unroll
          for (int r = 0; r < 4; r++){
            int row = wr*32 + fm*16 + lg*4 + r;
            int col = wc*32 + fn*16 + li;
            int chunk = col >> 3, within = col & 7;
            b_lds[row*128 + (chunk ^ (row & 7))*8 + within] = __float2half(acc[fm][fn][r]);
          }
      __syncthreads();
      // 64 rows x 16 chunks = 1024 chunks = 2 passes of 512 threads
      #pragma unroll
      for (int p = 0; p < 2; p++){
        int chunk = tid + p*512;
        int row = chunk >> 4, cs = chunk & 15;
        int gm = m0 + row;
        if (gm < nrows){
          int4 val = *(int4*)&b_lds[row*128 + (cs ^ (row & 7))*8];
          if (mat == 0)      *(int4*)&oq [(size_t)gm*128 + cs*8] = val;
          else if (mat == 3) *(int4*)&osk[(size_t)gm*128 + cs*8] = val;
          else if (mat == 2) *(int4*)&okv[(size_t)gm*384 + 128 + cs*16] = val;  // v fp16
          else {
            // k -> fp8 e4m3: 8 halves -> 8 bytes
            const __half2* hv = (const __half2*)&val;
            float2 f0 = __half22float2(hv[0]);
            float2 f1 = __half22float2(hv[1]);
            float2 f2 = __half22float2(hv[2]);
            float2 f3 = __half22float2(hv[3]);
            int2 wv;
            wv.x = (int)enc_fp8x4(f0.x, f0.y, f1.x, f1.y);
            wv.y = (int)enc_fp8x4(f2.x, f2.y, f3.x, f3.y);
            *(int2*)&okv[(size_t)gm*384 + cs*8] = wv;
          }
        }
      }
      __syncthreads();   // stores' LDS reads done before next B stage
    } else {
      float* f_lds = (float*)b_lds;   // 64x128 f32 = 32 KB
      #pragma unroll
      for (int fm = 0; fm < 2; fm++)
        #pragma unroll
        for (int fn = 0; fn < 2; fn++)
          #pragma unroll
          for (int r = 0; r < 4; r++){
            int row = wr*32 + fm*16 + lg*4 + r;
            int col = wc*32 + fn*16 + li;
            int chunk = col >> 2, within = col & 3;
            f_lds[row*128 + (chunk ^ (row & 7))*4 + within] = acc[fm][fn][r];
          }
      __syncthreads();
      // 64 rows x 32 fp32-chunks = 2048 chunks = 4 passes
      #pragma unroll
      for (int p = 0; p < 4; p++){
        int chunk = tid + p*512;
        int row = chunk >> 5, cs = chunk & 31;
        int gm = m0 + row;
        if (gm < nrows)
          *(int4*)&ofp[(size_t)gm*DD + cs*4] = *(int4*)&f_lds[row*128 + (cs ^ (row & 7))*4];
      }
    }
  }
}

// ======================= per-node attention aggregation (fp8 k) =======================
// wave per dst node (grid = ceil(N/4) blocks of 4 waves — R15 optimum; the
// persistent-wave variant regressed: consecutive short blocks give better
// CSR/q locality). 8 sub-streams of 8 lanes, lane owns ONE head's 16
// channels. kv record = 384B: [k fp8 128B | v fp16 256B]. No online max;
// 1-deep register prefetch.
__global__ __launch_bounds__(256) void agg_kernel(
    const __half* __restrict__ hq, const __half* __restrict__ hsk,
    const unsigned char* __restrict__ kv,
    const int* __restrict__ off, const int* __restrict__ csr_src,
    __half* __restrict__ xout, int n)
{
  int wid = blockIdx.x*4 + (threadIdx.x >> 6);
  if (wid >= n) return;
  int lane = threadIdx.x & 63;
  int sub  = lane >> 3;          // 0..7: edge sub-stream
  int h    = lane & 7;           // head index
  int c    = h*16;               // 16 channels per head per lane

  float qf[16];
  {
    int4 q0 = *(const int4*)&hq[(size_t)wid*DD + c];
    int4 q1 = *(const int4*)&hq[(size_t)wid*DD + c + 8];
    const __half2* qh = (const __half2*)&q0;
    #pragma unroll
    for (int i = 0; i < 4; i++){
      float2 f = __half22float2(qh[i]);
      qf[2*i] = f.x; qf[2*i+1] = f.y;
    }
    const __half2* qh1 = (const __half2*)&q1;
    #pragma unroll
    for (int i = 0; i < 4; i++){
      float2 f = __half22float2(qh1[i]);
      qf[8+2*i] = f.x; qf[8+2*i+1] = f.y;
    }
  }

  float z = 0.f;
  float acc[16];
  #pragma unroll
  for (int i = 0; i < 16; i++) acc[i] = 0.f;

  const int e1 = off[wid+1];
  int e = off[wid] + sub;
  int s2 = (e+8 < e1) ? csr_src[e+8] : -1;
  int4 kr, v0r, v1r;
  if (e < e1){
    const unsigned char* r = kv + (size_t)csr_src[e]*384;
    kr  = *(const int4*)(r + h*16);
    v0r = *(const int4*)(r + 128 + h*32);
    v1r = *(const int4*)(r + 144 + h*32);
  }
  while (e < e1){
    int4 kn, v0n, v1n;
    if (s2 >= 0){
      const unsigned char* r = kv + (size_t)s2*384;
      kn  = *(const int4*)(r + h*16);
      v0n = *(const int4*)(r + 128 + h*32);
      v1n = *(const int4*)(r + 144 + h*32);
    }
    int s3 = (e+16 < e1) ? csr_src[e+16] : -1;

    // decode 16 fp8 k values and dot with qf
    const unsigned int* kw = (const unsigned int*)&kr;
    float p = 0.f;
    #pragma unroll
    for (int i = 0; i < 4; i++){
      f32x2 a = dec_fp8_lo(kw[i]);
      f32x2 b = dec_fp8_hi(kw[i]);
      p += qf[4*i]*a[0] + qf[4*i+1]*a[1] + qf[4*i+2]*b[0] + qf[4*i+3]*b[1];
    }
    float wgt = __expf(p * 0.25f);     // 1/sqrt(16); no max subtraction

    const __half2* vh0 = (const __half2*)&v0r;
    const __half2* vh1 = (const __half2*)&v1r;
    #pragma unroll
    for (int i = 0; i < 4; i++){
      float2 f = __half22float2(vh0[i]);
      acc[2*i]   += wgt * f.x;
      acc[2*i+1] += wgt * f.y;
    }
    #pragma unroll
    for (int i = 0; i < 4; i++){
      float2 f = __half22float2(vh1[i]);
      acc[8+2*i]   += wgt * f.x;
      acc[8+2*i+1] += wgt * f.y;
    }
    z += wgt;

    kr = kn; v0r = v0n; v1r = v1n;
    s2 = s3; e += 8;
  }

  // merge 8 sub-streams (pure sums)
  #pragma unroll
  for (int d = 8; d <= 32; d <<= 1){
    z += __shfl_xor(z, d);
    #pragma unroll
    for (int i = 0; i < 16; i++)
      acc[i] += __shfl_xor(acc[i], d);
  }

  if (sub == 0){
    float inv = (z > 0.f) ? 1.f/z : 0.f;
    int4 s0 = *(const int4*)&hsk[(size_t)wid*DD + c];
    int4 s1 = *(const int4*)&hsk[(size_t)wid*DD + c + 8];
    const __half2* sh0 = (const __half2*)&s0;
    const __half2* sh1 = (const __half2*)&s1;
    __half2 po[4];
    #pragma unroll
    for (int i = 0; i < 4; i++){
      float2 s = __half22float2(sh0[i]);
      po[i] = __floats2half2_rn(fmaxf(acc[2*i]*inv + s.x, 0.f),
                                fmaxf(acc[2*i+1]*inv + s.y, 0.f));
    }
    *(int4*)&xout[(size_t)wid*DD + c] = *(const int4*)po;
    #pragma unroll
    for (int i = 0; i < 4; i++){
      float2 s = __half22float2(sh1[i]);
      po[i] = __floats2half2_rn(fmaxf(acc[8+2*i]*inv + s.x, 0.f),
                                fmaxf(acc[8+2*i+1]*inv + s.y, 0.f));
    }
    *(int4*)&xout[(size_t)wid*DD + c + 8] = *(const int4*)po;
  }
}

// ======================= launch =======================

extern "C" void kernel_launch(void* const* d_in, const int* in_sizes, int n_in,
                              void* d_out, int out_size, void* d_ws, size_t ws_size,
                              hipStream_t stream) {
  const float* x     = (const float*)d_in[0];
  const int*   edge  = (const int*)d_in[1];
  const int*   esrc  = edge;
  const int*   edst  = edge + EE;
  const float* Wq    = (const float*)d_in[3];
  const float* bq    = (const float*)d_in[4];
  const float* Wk    = (const float*)d_in[5];
  const float* bk    = (const float*)d_in[6];
  const float* Wv    = (const float*)d_in[7];
  const float* bv    = (const float*)d_in[8];
  const float* Wsk   = (const float*)d_in[9];
  const float* bsk   = (const float*)d_in[10];
  const float* Wout  = (const float*)d_in[11];
  const float* bout  = (const float*)d_in[12];
  float* out = (float*)d_out;

  uintptr_t base = (uintptr_t)d_ws;
  auto align = [](uintptr_t p){ return (p + 255) & ~(uintptr_t)255; };
  int* deg    = (int*)base;  base = align(base + (NN+1)*sizeof(int));
  int* off    = (int*)base;  base = align(base + (NN+1)*sizeof(int));
  int* rank   = (int*)base;  base = align(base + (size_t)EE*sizeof(int));
  int* bsum   = (int*)base;  base = align(base + 256*sizeof(int));
  int* csr    = (int*)base;  base = align(base + (size_t)EE*sizeof(int));
  __half* xh   = (__half*)base; base = align(base + (size_t)NN*DD*sizeof(__half));
  __half* xbuf = (__half*)base; base = align(base + (size_t)NN*DD*sizeof(__half));
  __half* hq   = (__half*)base; base = align(base + (size_t)NN*DD*sizeof(__half));
  __half* hsk  = (__half*)base; base = align(base + (size_t)NN*DD*sizeof(__half));
  unsigned char* kvb = (unsigned char*)base; base = align(base + (size_t)NN*384);
  __half* wt   = (__half*)base; base = align(base + (size_t)4*512*128*sizeof(__half));
  __half* wtout= (__half*)base; base = align(base + (size_t)128*128*sizeof(__half));
  float*  bcat = (float*)base;  base = align(base + (size_t)4*512*sizeof(float));

  const int NP = NN + 1;
  const int SCAN_BLKS = (NP + 255)/256;

  zero_kernel<<<SCAN_BLKS, 256, 0, stream>>>(deg, NP);
  hist_kernel<<<(EE+255)/256, 256, 0, stream>>>(edst, deg, rank, EE);
  scan_partial<<<SCAN_BLKS, 256, 0, stream>>>(deg, bsum, NP);
  scan_bsums<<<1, 256, 0, stream>>>(bsum, SCAN_BLKS);
  scan_apply<<<SCAN_BLKS, 256, 0, stream>>>(deg, bsum, off, NP);
  scatter_kernel<<<(EE+255)/256, 256, 0, stream>>>(esrc, edst, rank, off, csr, EE);

  prep_w<<<1024, 256, 0, stream>>>(Wq, Wk, Wv, Wsk, bq, bk, bv, bsk, Wout, wt, bcat, wtout);
  convert_x<<<(NN*DD/8 + 255)/256, 256, 0, stream>>>(x, xh, NN*DD/8);

  const int MT64 = (NN + 63)/64;   // 782 row tiles
  const __half* xin = xh;
  for (int l = 0; l < 4; l++){
    mfma_gemm<0><<<MT64, 512, 0, stream>>>(
        xin, wt + (size_t)l*512*128, bcat + l*512,
        hq, kvb, hsk, nullptr, NN);
    agg_kernel<<<(NN+3)/4, 256, 0, stream>>>(hq, hsk, kvb, off, csr, xbuf, NN);
    xin = xbuf;
  }
  mfma_gemm<1><<<MT64, 512, 0, stream>>>(
      xin, wtout, bout, nullptr, kvb, nullptr, out, NN);
}